// Round 11
// baseline (71.509 us; speedup 1.0000x reference)
//
#include <hip/hip_runtime.h>
#include <math.h>

#define CC 128
#define TWO_C 256
#define NT 8
#define HH 64
#define DD 16

typedef short bf16x8 __attribute__((ext_vector_type(8)));
typedef float f32x4 __attribute__((ext_vector_type(4)));

static __device__ __forceinline__ unsigned short f2bf_rne(float f) {
    union { float f; unsigned int u; } v; v.f = f;
    unsigned int r = (v.u + 0x7fffu + ((v.u >> 16) & 1u)) >> 16;
    return (unsigned short)r;
}
static __device__ __forceinline__ unsigned int pkbf(float a, float b) {
    unsigned int ua = __float_as_uint(a) + 0x8000u;
    unsigned int ub = __float_as_uint(b) + 0x8000u;
    return (ua >> 16) | (ub & 0xffff0000u);
}
static __device__ __forceinline__ void glds16(const void* g, void* l) {
    __builtin_amdgcn_global_load_lds(
        (const __attribute__((address_space(1))) void*)g,
        (__attribute__((address_space(3))) void*)l, 16, 0, 0);
}

// ---------------- P0 (fused): weight pack + s1/c1 + x->bf16 + S,Q  ∥  direct scatter
// tid segments: [0,16384) W1p | [16384,17408) W2p | [17408,50176) s1/c1
//               [50176, 50176+Nn*16) xb+SQ | [scatterTidBase, +hq) scatter (block-aligned)
// Pack and scatter are DATA-INDEPENDENT -> safe to co-schedule in one grid, no fences.
__global__ __launch_bounds__(256) void pack_scatter_kernel(
    const float* __restrict__ W1, const float* __restrict__ W2,
    const float* __restrict__ gamma, const float* __restrict__ beta,
    const float* __restrict__ b1, const float* __restrict__ x,
    unsigned short* __restrict__ W1p, unsigned short* __restrict__ W2p,
    float* __restrict__ s1g, float* __restrict__ c1g,
    unsigned short* __restrict__ xb, float2* __restrict__ SQ, int Nnodes,
    const int* __restrict__ et, const int* __restrict__ ei,
    int* __restrict__ cursor,
    int* __restrict__ srowD, int* __restrict__ scolD, int* __restrict__ invD,
    int E, int capE, int scatterTidBase)
{
    const int tid = blockIdx.x * 256 + threadIdx.x;
    __shared__ int lh[NT], lbase[NT];

    if (tid < scatterTidBase) {
        if (tid < 16384) {
            int l = tid & 63, kt = (tid >> 6) & 7, nt = (tid >> 9) & 3, t = tid >> 11;
            int n = nt * 16 + (l & 15);
            int k0 = kt * 32 + (l >> 4) * 8;
            #pragma unroll
            for (int j = 0; j < 8; ++j) {
                int k = k0 + j;
                float v = gamma[t * TWO_C + k] * W1[(size_t)t * TWO_C * HH + (size_t)k * HH + n];
                W1p[tid * 8 + j] = f2bf_rne(v);
            }
        } else if (tid < 17408) {
            int s = tid - 16384;
            int l = s & 63, kt = (s >> 6) & 1, t = s >> 7;
            int n = l & 15;
            int k0 = kt * 32 + (l >> 4) * 8;
            #pragma unroll
            for (int j = 0; j < 8; ++j)
                W2p[s * 8 + j] = f2bf_rne(W2[(size_t)t * HH * DD + (size_t)(k0 + j) * DD + n]);
        } else if (tid < 50176) {
            // one 64-lane wave per (t,n)
            int id = tid - 17408;
            int lane = id & 63;
            int pair = id >> 6;
            int t = pair >> 6, n = pair & 63;
            float sa = 0.f, ca = 0.f;
            #pragma unroll
            for (int i = 0; i < 4; ++i) {
                int k = i * 64 + lane;
                float wv = W1[(size_t)t * TWO_C * HH + (size_t)k * HH + n];
                sa = fmaf(gamma[t * TWO_C + k], wv, sa);
                ca = fmaf(beta[t * TWO_C + k], wv, ca);
            }
            #pragma unroll
            for (int off = 1; off < 64; off <<= 1) {
                sa += __shfl_xor(sa, off);
                ca += __shfl_xor(ca, off);
            }
            if (lane == 0) {
                s1g[pair] = sa;
                c1g[pair] = ca + b1[pair];
            }
        } else {
            int idx = tid - 50176;
            int v = idx >> 4;
            if (v < Nnodes) {
                int ll = idx & 15;
                int base = idx * 8;
                float4 p = *(const float4*)(x + base);
                float4 q = *(const float4*)(x + base + 4);
                uint4 u;
                u.x = pkbf(p.x, p.y); u.y = pkbf(p.z, p.w);
                u.z = pkbf(q.x, q.y); u.w = pkbf(q.z, q.w);
                *(uint4*)(xb + base) = u;
                float s  = p.x + p.y + p.z + p.w + q.x + q.y + q.z + q.w;
                float sq = p.x*p.x + p.y*p.y + p.z*p.z + p.w*p.w
                         + q.x*q.x + q.y*q.y + q.z*q.z + q.w*q.w;
                #pragma unroll
                for (int off = 1; off < 16; off <<= 1) {
                    s  += __shfl_xor(s, off);
                    sq += __shfl_xor(sq, off);
                }
                if (ll == 0) SQ[v] = make_float2(s, sq);
            }
        }
    } else {
        // ---- scatter role (whole block uniform; scatterTidBase is 256-aligned) ----
        if (threadIdx.x < NT) lh[threadIdx.x] = 0;
        __syncthreads();
        int i0 = (tid - scatterTidBase) * 4;
        int tl[4], rk[4];
        #pragma unroll
        for (int j = 0; j < 4; ++j) {
            int i = i0 + j;
            if (i < E) { tl[j] = et[i]; rk[j] = atomicAdd(&lh[tl[j]], 1); }
        }
        __syncthreads();
        if (threadIdx.x < NT)
            lbase[threadIdx.x] = lh[threadIdx.x] ? atomicAdd(&cursor[threadIdx.x], lh[threadIdx.x]) : 0;
        __syncthreads();
        #pragma unroll
        for (int j = 0; j < 4; ++j) {
            int i = i0 + j;
            if (i < E) {
                int slot = tl[j] * capE + lbase[tl[j]] + rk[j];
                srowD[slot] = ei[i];
                scolD[slot] = ei[E + i];
                invD[i] = slot;
            }
        }
    }
}

// ---------------- fallback prep: hist / scan / scatter (po-based) ----------------
__global__ __launch_bounds__(256) void hist_kernel(const int* __restrict__ et,
                                                   int* __restrict__ counts, int E)
{
    __shared__ int lh[NT];
    if (threadIdx.x < NT) lh[threadIdx.x] = 0;
    __syncthreads();
    int i0 = (blockIdx.x * 256 + threadIdx.x) * 4;
    #pragma unroll
    for (int j = 0; j < 4; ++j)
        if (i0 + j < E) atomicAdd(&lh[et[i0 + j]], 1);
    __syncthreads();
    if (threadIdx.x < NT && lh[threadIdx.x]) atomicAdd(&counts[threadIdx.x], lh[threadIdx.x]);
}

__global__ void scan_kernel(const int* __restrict__ counts, int* __restrict__ po,
                            int* __restrict__ cursor)
{
    if (threadIdx.x == 0 && blockIdx.x == 0) {
        int acc = 0;
        for (int t = 0; t < NT; ++t) {
            po[t] = acc;
            cursor[t] = acc;
            acc += ((counts[t] + 63) >> 6) << 6;
        }
        po[NT] = acc;
    }
}

__global__ __launch_bounds__(256) void scatter_kernel(const int* __restrict__ et,
                                                      const int* __restrict__ ei,
                                                      int* __restrict__ cursor,
                                                      int* __restrict__ sorted,
                                                      int* __restrict__ srow,
                                                      int* __restrict__ scol,
                                                      int E)
{
    __shared__ int lh[NT], lbase[NT];
    if (threadIdx.x < NT) lh[threadIdx.x] = 0;
    __syncthreads();
    int i0 = (blockIdx.x * 256 + threadIdx.x) * 4;
    int tl[4], rk[4];
    #pragma unroll
    for (int j = 0; j < 4; ++j) {
        int i = i0 + j;
        if (i < E) { tl[j] = et[i]; rk[j] = atomicAdd(&lh[tl[j]], 1); }
    }
    __syncthreads();
    if (threadIdx.x < NT)
        lbase[threadIdx.x] = lh[threadIdx.x] ? atomicAdd(&cursor[threadIdx.x], lh[threadIdx.x]) : 0;
    __syncthreads();
    #pragma unroll
    for (int j = 0; j < 4; ++j) {
        int i = i0 + j;
        if (i < E) {
            int slot = lbase[tl[j]] + rk[j];
            sorted[slot] = i;
            srow[slot] = ei[i];
            scol[slot] = ei[E + i];
        }
    }
}

// LDS map: [0,16384) xhat bf16 [64][256B] XOR-swz; h1 [64][144B] aliased
//          [16384,16896) stats; [16896,17152) sid; [17152,17408) rbuf; [17408,17664) cbuf
#define XHAT_OFF 0
#define H1_OFF   0
#define STATS_OFF 16384
#define SID_OFF   16896
#define RB_OFF    17152
#define CB_OFF    17408
#define LDS_BYTES 17664

// ---------------- main: FIXED=1 arithmetic segments + tmp write; FIXED=0 po-search ----
template <int FIXED>
__global__ __launch_bounds__(256, 8) void sheaf_main_full(
    const unsigned short* __restrict__ xb, const float* __restrict__ b2,
    const unsigned short* __restrict__ W1p, const unsigned short* __restrict__ W2p,
    const float* __restrict__ s1g, const float* __restrict__ c1g,
    const float2* __restrict__ SQ,
    const int* __restrict__ po, const int* __restrict__ counts,
    const int* __restrict__ sorted, const int* __restrict__ srow,
    const int* __restrict__ scol,
    float* __restrict__ dst, int bpt, int capE)
{
    __shared__ __align__(16) unsigned char lds[LDS_BYTES];
    int t, base, lim, segBase;
    if (FIXED) {
        t = blockIdx.x / bpt;
        int inb = (blockIdx.x - t * bpt) * 64;
        lim = counts[t];
        if (inb >= lim) return;
        segBase = t * capE;
        base = segBase + inb;
        lim += segBase;
    } else {
        base = blockIdx.x * 64;
        if (base >= po[NT]) return;
        t = 0;
        while (base >= po[t + 1]) ++t;
        lim = po[t] + counts[t];
        if (base >= lim) return;
        segBase = po[t];
    }

    const int tid = threadIdx.x;
    const int w = tid >> 6, lane = tid & 63;
    const int lg = lane >> 4, ll = lane & 15;

    int* sid  = (int*)(lds + SID_OFF);
    int* rbuf = (int*)(lds + RB_OFF);
    int* cbuf = (int*)(lds + CB_OFF);
    float2* stats = (float2*)(lds + STATS_OFF);

    if (tid < 64) {
        int slot = base + tid;
        int src = slot < lim ? slot : segBase;
        rbuf[tid] = srow[src];
        cbuf[tid] = scol[src];
        if (!FIXED) sid[tid] = sorted[src];
    }
    __syncthreads();

    #pragma unroll
    for (int i = 0; i < 4; ++i) {
        const int el = w * 16 + i * 4 + lg;
        const unsigned short* src = xb + (size_t)rbuf[el] * CC + ((ll ^ (el & 7)) * 8);
        glds16(src, lds + XHAT_OFF + (w * 16 + i * 4) * 256);
    }
    if (tid < 64) {
        float2 a = SQ[rbuf[tid]];
        float2 b = SQ[cbuf[tid]];
        float mu  = (a.x + b.x) * (1.0f / TWO_C);
        float var = (a.y + b.y) * (1.0f / TWO_C) - mu * mu;
        stats[tid] = make_float2(mu, rsqrtf(var + 1e-5f));
    }
    __syncthreads();

    f32x4 acc[4];
    #pragma unroll
    for (int mt = 0; mt < 4; ++mt) acc[mt] = (f32x4){0.f, 0.f, 0.f, 0.f};
    const bf16x8* Bp = (const bf16x8*)W1p + (size_t)((t * 4 + w) * 8) * 64 + lane;
    #pragma unroll
    for (int kt = 0; kt < 4; ++kt) {
        bf16x8 bfrag = Bp[kt * 64];
        #pragma unroll
        for (int mt = 0; mt < 4; ++mt) {
            int row = mt * 16 + ll;
            bf16x8 afrag = *(const bf16x8*)(lds + XHAT_OFF + row * 256 +
                                            ((kt * 64 + lg * 16) ^ ((row & 7) << 4)));
            acc[mt] = __builtin_amdgcn_mfma_f32_16x16x32_bf16(afrag, bfrag, acc[mt], 0, 0, 0);
        }
    }
    __syncthreads();

    #pragma unroll
    for (int i = 0; i < 4; ++i) {
        const int el = w * 16 + i * 4 + lg;
        const unsigned short* src = xb + (size_t)cbuf[el] * CC + ((ll ^ (el & 7)) * 8);
        glds16(src, lds + XHAT_OFF + (w * 16 + i * 4) * 256);
    }
    __syncthreads();

    #pragma unroll
    for (int kt = 0; kt < 4; ++kt) {
        bf16x8 bfrag = Bp[(4 + kt) * 64];
        #pragma unroll
        for (int mt = 0; mt < 4; ++mt) {
            int row = mt * 16 + ll;
            bf16x8 afrag = *(const bf16x8*)(lds + XHAT_OFF + row * 256 +
                                            ((kt * 64 + lg * 16) ^ ((row & 7) << 4)));
            acc[mt] = __builtin_amdgcn_mfma_f32_16x16x32_bf16(afrag, bfrag, acc[mt], 0, 0, 0);
        }
    }
    __syncthreads();

    const int n = w * 16 + ll;
    const float s1v = s1g[t * HH + n];
    const float c1v = c1g[t * HH + n];
    #pragma unroll
    for (int mt = 0; mt < 4; ++mt) {
        #pragma unroll
        for (int j = 0; j < 4; ++j) {
            int el = mt * 16 + lg * 4 + j;
            float2 st = stats[el];
            float z = st.y * (acc[mt][j] - st.x * s1v) + c1v;
            z = fmaxf(z, 0.0f);
            *(unsigned short*)(lds + H1_OFF + el * 144 + n * 2) =
                (unsigned short)((__float_as_uint(z) + 0x8000u) >> 16);
        }
    }
    __syncthreads();

    f32x4 acc2 = (f32x4){0.f, 0.f, 0.f, 0.f};
    #pragma unroll
    for (int kt = 0; kt < 2; ++kt) {
        bf16x8 bfrag = ((const bf16x8*)W2p)[(t * 2 + kt) * 64 + lane];
        bf16x8 afrag = *(const bf16x8*)(lds + H1_OFF + (w * 16 + ll) * 144 + kt * 64 + lg * 16);
        acc2 = __builtin_amdgcn_mfma_f32_16x16x32_bf16(afrag, bfrag, acc2, 0, 0, 0);
    }

    const float b2v = b2[t * DD + ll];
    const float diag = ((ll >> 2) == (ll & 3)) ? 1.0f : 0.0f;
    #pragma unroll
    for (int j = 0; j < 4; ++j) {
        float o = acc2[j] + b2v;
        float m = fmaxf(o, __shfl_xor(o, 1));
        m = fmaxf(m, __shfl_xor(m, 2));
        float p = __expf(o - m);
        float su = p + __shfl_xor(p, 1);
        su += __shfl_xor(su, 2);
        float res = diag - p / su;
        int el = w * 16 + lg * 4 + j;
        if (FIXED) dst[(size_t)(base + el) * DD + ll] = res;
        else       dst[(size_t)sid[el] * DD + ll] = res;
    }
}

// ---------------- tiny fallback: f32 gather, in-kernel stats ----------------
__global__ __launch_bounds__(256, 8) void sheaf_main_fb(
    const float* __restrict__ x, const float* __restrict__ b2,
    const unsigned short* __restrict__ W1p, const unsigned short* __restrict__ W2p,
    const float* __restrict__ s1g, const float* __restrict__ c1g,
    const int* __restrict__ po, const int* __restrict__ counts,
    const int* __restrict__ sorted, const int* __restrict__ srow,
    const int* __restrict__ scol,
    float* __restrict__ out)
{
    __shared__ __align__(16) unsigned char lds[LDS_BYTES];
    const int base = blockIdx.x * 64;
    if (base >= po[NT]) return;
    int t = 0;
    while (base >= po[t + 1]) ++t;
    const int lim = po[t] + counts[t];
    if (base >= lim) return;

    const int tid = threadIdx.x;
    const int w = tid >> 6, lane = tid & 63;
    const int lg = lane >> 4, ll = lane & 15;
    int* sid  = (int*)(lds + SID_OFF);
    int* rbuf = (int*)(lds + RB_OFF);
    int* cbuf = (int*)(lds + CB_OFF);

    if (tid < 64) {
        int slot = base + tid;
        int src = slot < lim ? slot : po[t];
        rbuf[tid] = srow[src]; cbuf[tid] = scol[src]; sid[tid] = sorted[src];
    }
    __syncthreads();

    float s[4] = {0,0,0,0}, sq[4] = {0,0,0,0};
    #pragma unroll
    for (int i = 0; i < 4; ++i) {
        const int el = w * 16 + i * 4 + lg;
        const float4* px = (const float4*)(x + (size_t)rbuf[el] * CC + ll * 8);
        float4 p = px[0], q = px[1];
        s[i] += p.x+p.y+p.z+p.w+q.x+q.y+q.z+q.w;
        sq[i] = fmaf(p.x,p.x,sq[i]); sq[i] = fmaf(p.y,p.y,sq[i]);
        sq[i] = fmaf(p.z,p.z,sq[i]); sq[i] = fmaf(p.w,p.w,sq[i]);
        sq[i] = fmaf(q.x,q.x,sq[i]); sq[i] = fmaf(q.y,q.y,sq[i]);
        sq[i] = fmaf(q.z,q.z,sq[i]); sq[i] = fmaf(q.w,q.w,sq[i]);
        uint4 u;
        u.x = pkbf(p.x,p.y); u.y = pkbf(p.z,p.w); u.z = pkbf(q.x,q.y); u.w = pkbf(q.z,q.w);
        *(uint4*)(lds + XHAT_OFF + el * 256 + ((ll * 16) ^ ((el & 7) << 4))) = u;
    }
    __syncthreads();

    f32x4 acc[4];
    #pragma unroll
    for (int mt = 0; mt < 4; ++mt) acc[mt] = (f32x4){0.f,0.f,0.f,0.f};
    const bf16x8* Bp = (const bf16x8*)W1p + (size_t)((t * 4 + w) * 8) * 64 + lane;
    #pragma unroll
    for (int kt = 0; kt < 4; ++kt) {
        bf16x8 bfrag = Bp[kt * 64];
        #pragma unroll
        for (int mt = 0; mt < 4; ++mt) {
            int row = mt * 16 + ll;
            bf16x8 afrag = *(const bf16x8*)(lds + XHAT_OFF + row * 256 +
                                            ((kt * 64 + lg * 16) ^ ((row & 7) << 4)));
            acc[mt] = __builtin_amdgcn_mfma_f32_16x16x32_bf16(afrag, bfrag, acc[mt], 0, 0, 0);
        }
    }
    __syncthreads();

    #pragma unroll
    for (int i = 0; i < 4; ++i) {
        const int el = w * 16 + i * 4 + lg;
        const float4* px = (const float4*)(x + (size_t)cbuf[el] * CC + ll * 8);
        float4 p = px[0], q = px[1];
        s[i] += p.x+p.y+p.z+p.w+q.x+q.y+q.z+q.w;
        sq[i] = fmaf(p.x,p.x,sq[i]); sq[i] = fmaf(p.y,p.y,sq[i]);
        sq[i] = fmaf(p.z,p.z,sq[i]); sq[i] = fmaf(p.w,p.w,sq[i]);
        sq[i] = fmaf(q.x,q.x,sq[i]); sq[i] = fmaf(q.y,q.y,sq[i]);
        sq[i] = fmaf(q.z,q.z,sq[i]); sq[i] = fmaf(q.w,q.w,sq[i]);
        uint4 u;
        u.x = pkbf(p.x,p.y); u.y = pkbf(p.z,p.w); u.z = pkbf(q.x,q.y); u.w = pkbf(q.z,q.w);
        *(uint4*)(lds + XHAT_OFF + el * 256 + ((ll * 16) ^ ((el & 7) << 4))) = u;
    }
    float2* stats = (float2*)(lds + STATS_OFF);
    #pragma unroll
    for (int i = 0; i < 4; ++i) {
        float s_ = s[i], q_ = sq[i];
        #pragma unroll
        for (int off = 1; off < 16; off <<= 1) {
            s_ += __shfl_xor(s_, off); q_ += __shfl_xor(q_, off);
        }
        if (ll == 0) {
            float mu = s_ * (1.0f / TWO_C);
            float var = q_ * (1.0f / TWO_C) - mu * mu;
            stats[w * 16 + i * 4 + lg] = make_float2(mu, rsqrtf(var + 1e-5f));
        }
    }
    __syncthreads();

    #pragma unroll
    for (int kt = 0; kt < 4; ++kt) {
        bf16x8 bfrag = Bp[(4 + kt) * 64];
        #pragma unroll
        for (int mt = 0; mt < 4; ++mt) {
            int row = mt * 16 + ll;
            bf16x8 afrag = *(const bf16x8*)(lds + XHAT_OFF + row * 256 +
                                            ((kt * 64 + lg * 16) ^ ((row & 7) << 4)));
            acc[mt] = __builtin_amdgcn_mfma_f32_16x16x32_bf16(afrag, bfrag, acc[mt], 0, 0, 0);
        }
    }
    __syncthreads();

    const int n = w * 16 + ll;
    const float s1v = s1g[t * HH + n];
    const float c1v = c1g[t * HH + n];
    #pragma unroll
    for (int mt = 0; mt < 4; ++mt) {
        #pragma unroll
        for (int j = 0; j < 4; ++j) {
            int el = mt * 16 + lg * 4 + j;
            float2 st = stats[el];
            float z = st.y * (acc[mt][j] - st.x * s1v) + c1v;
            z = fmaxf(z, 0.0f);
            *(unsigned short*)(lds + H1_OFF + el * 144 + n * 2) =
                (unsigned short)((__float_as_uint(z) + 0x8000u) >> 16);
        }
    }
    __syncthreads();

    f32x4 acc2 = (f32x4){0.f,0.f,0.f,0.f};
    #pragma unroll
    for (int kt = 0; kt < 2; ++kt) {
        bf16x8 bfrag = ((const bf16x8*)W2p)[(t * 2 + kt) * 64 + lane];
        bf16x8 afrag = *(const bf16x8*)(lds + H1_OFF + (w * 16 + ll) * 144 + kt * 64 + lg * 16);
        acc2 = __builtin_amdgcn_mfma_f32_16x16x32_bf16(afrag, bfrag, acc2, 0, 0, 0);
    }
    const float b2v = b2[t * DD + ll];
    const float diag = ((ll >> 2) == (ll & 3)) ? 1.0f : 0.0f;
    #pragma unroll
    for (int j = 0; j < 4; ++j) {
        float o = acc2[j] + b2v;
        float m = fmaxf(o, __shfl_xor(o, 1));
        m = fmaxf(m, __shfl_xor(m, 2));
        float p = __expf(o - m);
        float su = p + __shfl_xor(p, 1);
        su += __shfl_xor(su, 2);
        int el = w * 16 + lg * 4 + j;
        out[(size_t)sid[el] * DD + ll] = diag - p / su;
    }
}

// ---------------- permute: one edge per thread (64B copy) ----------------
__global__ __launch_bounds__(256) void permute_kernel(const float4* __restrict__ tmp,
                                                      const int* __restrict__ inv,
                                                      float4* __restrict__ out, int E)
{
    int e = blockIdx.x * 256 + threadIdx.x;
    if (e >= E) return;
    int slot = inv[e];
    const float4* s = tmp + (size_t)slot * 4;
    float4 a = s[0], b = s[1], c = s[2], d = s[3];
    float4* o = out + (size_t)e * 4;
    o[0] = a; o[1] = b; o[2] = c; o[3] = d;
}

extern "C" void kernel_launch(void* const* d_in, const int* in_sizes, int n_in,
                              void* d_out, int out_size, void* d_ws, size_t ws_size,
                              hipStream_t stream) {
    const float* x          = (const float*)d_in[0];
    const int*   edge_index = (const int*)  d_in[1];
    const int*   edge_types = (const int*)  d_in[2];
    const float* gamma      = (const float*)d_in[3];
    const float* beta       = (const float*)d_in[4];
    const float* W1         = (const float*)d_in[5];
    const float* b1         = (const float*)d_in[6];
    const float* W2         = (const float*)d_in[7];
    const float* b2         = (const float*)d_in[8];
    float* out = (float*)d_out;

    const int E = in_sizes[2];
    const int xtotal = in_sizes[0];
    const int Nn = xtotal / CC;
    const int hq = (E + 3) / 4;

    const size_t pack_bytes = (size_t)NT * 4 * 8 * 64 * 8 * 2
                            + (size_t)NT * 2 * 64 * 8 * 2
                            + (size_t)NT * HH * 4 * 2;

    int* ws_i   = (int*)d_ws;
    int* counts = ws_i;          // direct: cursor/counts;  fallback: counts
    int* cursor = ws_i + 16;     // fallback cursor
    int* po     = ws_i + 24;     // fallback po

    // ======== direct layout: hdr | srow[segs] | scol[segs] | inv | packW | SQ | xb | tmp
    const int capE = (E + 63) & ~63;
    const int bpt  = capE / 64;
    const size_t segs = (size_t)capE * NT;
    size_t srow_d_off = 256;
    size_t scol_d_off = srow_d_off + segs * 4;
    size_t inv_d_off  = scol_d_off + segs * 4;
    size_t pk_d_off   = (inv_d_off + (size_t)E * 4 + 255) & ~(size_t)255;
    size_t sq_d_off   = (pk_d_off + pack_bytes + 255) & ~(size_t)255;
    size_t xb_d_off   = (sq_d_off + (size_t)Nn * 8 + 255) & ~(size_t)255;
    size_t tmp_d_off  = (xb_d_off + (size_t)xtotal * 2 + 255) & ~(size_t)255;
    size_t direct_end = tmp_d_off + segs * DD * 4;
    const int use_direct = (ws_size >= direct_end) ? 1 : 0;

    if (use_direct) {
        int* srow = (int*)((char*)d_ws + srow_d_off);
        int* scol = (int*)((char*)d_ws + scol_d_off);
        int* inv  = (int*)((char*)d_ws + inv_d_off);
        unsigned short* W1p = (unsigned short*)((char*)d_ws + pk_d_off);
        unsigned short* W2p = W1p + (size_t)NT * 4 * 8 * 64 * 8;
        float* s1g = (float*)(W2p + (size_t)NT * 2 * 64 * 8);
        float* c1g = s1g + NT * HH;
        float2* SQ = (float2*)((char*)d_ws + sq_d_off);
        unsigned short* xb = (unsigned short*)((char*)d_ws + xb_d_off);
        float* tmp = (float*)((char*)d_ws + tmp_d_off);

        hipMemsetAsync(counts, 0, 64, stream);
        // block-aligned scatter segment appended to the pack grid
        const int scatterTidBase = ((50176 + Nn * 16 + 255) / 256) * 256;
        const int totalT = scatterTidBase + ((hq + 255) / 256) * 256;
        hipLaunchKernelGGL(pack_scatter_kernel, dim3(totalT / 256), dim3(256), 0, stream,
                           W1, W2, gamma, beta, b1, x, W1p, W2p, s1g, c1g, xb, SQ, Nn,
                           edge_types, edge_index, counts, srow, scol, inv,
                           E, capE, scatterTidBase);
        hipLaunchKernelGGL((sheaf_main_full<1>), dim3(NT * bpt), dim3(256), 0, stream,
                           xb, b2, W1p, W2p, s1g, c1g, SQ, counts, counts,
                           (const int*)0, srow, scol, tmp, bpt, capE);
        hipLaunchKernelGGL(permute_kernel, dim3((E + 255) / 256), dim3(256), 0, stream,
                           (const float4*)tmp, inv, (float4*)out, E);
        return;
    }

    // ======== fallback layouts (po-based) ========
    const int cap = capE + 512;
    int* sorted = ws_i + 40;
    int* srow   = sorted + cap;
    int* scol   = srow + cap;
    size_t pk_off = (((size_t)(40 + 3 * (size_t)cap)) * 4 + 255) & ~(size_t)255;
    unsigned short* W1p = (unsigned short*)((char*)d_ws + pk_off);
    unsigned short* W2p = W1p + (size_t)NT * 4 * 8 * 64 * 8;
    float* s1g = (float*)(W2p + (size_t)NT * 2 * 64 * 8);
    float* c1g = s1g + NT * HH;
    size_t sq_off = (pk_off + pack_bytes + 255) & ~(size_t)255;
    float2* SQ = (float2*)((char*)d_ws + sq_off);
    size_t xb_off = (sq_off + (size_t)Nn * 8 + 255) & ~(size_t)255;
    unsigned short* xb = (unsigned short*)((char*)d_ws + xb_off);
    const size_t xb_end = xb_off + (size_t)xtotal * 2;
    const int use_full = (ws_size >= xb_end) ? 1 : 0;

    hipMemsetAsync(counts, 0, 32, stream);
    const int pt = use_full ? (50176 + Nn * 16) : 50176;
    // scatterTidBase beyond grid -> pack roles only
    hipLaunchKernelGGL(pack_scatter_kernel, dim3((pt + 255) / 256), dim3(256), 0, stream,
                       W1, W2, gamma, beta, b1, x, W1p, W2p, s1g, c1g,
                       xb, SQ, use_full ? Nn : 0,
                       edge_types, edge_index, cursor,
                       (int*)0, (int*)0, (int*)0, 0, 0, 0x7fffff00);
    hipLaunchKernelGGL(hist_kernel, dim3((hq + 255) / 256), dim3(256), 0, stream,
                       edge_types, counts, E);
    hipLaunchKernelGGL(scan_kernel, dim3(1), dim3(64), 0, stream, counts, po, cursor);
    hipLaunchKernelGGL(scatter_kernel, dim3((hq + 255) / 256), dim3(256), 0, stream,
                       edge_types, edge_index, cursor, sorted, srow, scol, E);

    const int gmain = cap / 64;
    if (use_full)
        hipLaunchKernelGGL((sheaf_main_full<0>), dim3(gmain), dim3(256), 0, stream,
                           xb, b2, W1p, W2p, s1g, c1g, SQ, po, counts,
                           sorted, srow, scol, out, 0, 0);
    else
        hipLaunchKernelGGL(sheaf_main_fb, dim3(gmain), dim3(256), 0, stream,
                           x, b2, W1p, W2p, s1g, c1g, po, counts,
                           sorted, srow, scol, out);
}